// Round 19
// baseline (127.150 us; speedup 1.0000x reference)
//
#include <hip/hip_runtime.h>
#include <hip/hip_bf16.h>
#include <math.h>

#define NB 32
#define NS 1024
#define NH 512
#define NE 1024   // 2H
#define NEGV -1e10f

typedef _Float16 f16x8 __attribute__((ext_vector_type(8)));
typedef _Float16 f16x4 __attribute__((ext_vector_type(4)));
typedef float f32x4 __attribute__((ext_vector_type(4)));

__device__ __forceinline__ float fast_tanh(float x) {
  float t = __expf(2.f * x);
  return (t - 1.f) * __builtin_amdgcn_rcpf(t + 1.f);
}

// c[b][h] = b_attn[h] + sum_e hidden[b][e] * W_h[e][h]   (fp32, tiny)
__global__ __launch_bounds__(256) void proj_h_kernel(
    const float* __restrict__ hidden, const float* __restrict__ W_attn,
    const float* __restrict__ b_attn, float* __restrict__ c) {
  int b = blockIdx.x >> 1;
  int h = ((blockIdx.x & 1) << 8) + threadIdx.x;
  __shared__ float hid[NH];
  for (int e = threadIdx.x; e < NH; e += 256) hid[e] = hidden[b * NH + e];
  __syncthreads();
  float acc = b_attn[h];
#pragma unroll 8
  for (int e = 0; e < NH; ++e) acc = fmaf(hid[e], W_attn[(size_t)e * NH + h], acc);
  c[b * NH + h] = acc;
}

// Pack W_e into MFMA B-fragment order. BYTE layout (R14-verified):
//   (ks*8 + wslice)*4096 + nj*1024 + lane*16  <-  halfs j=0..7 of
//   W_e[ks*32 + (lane>>4)*8 + j][wslice*64 + nj*16 + (lane&15)]
__global__ __launch_bounds__(256) void prep_We_kernel(
    const float* __restrict__ W_attn, _Float16* __restrict__ Bp) {
  int ks = blockIdx.x;  // 0..31
  int t = threadIdx.x;
#pragma unroll
  for (int p = 0; p < 8; ++p) {
    int f = (p << 8) + t;        // 0..2047
    int ws = f >> 8;             // 0..7  (64-col slice)
    int nj = (f >> 6) & 3;       // 0..3
    int lane = f & 63;
    int col = (ws << 6) + (nj << 4) + (lane & 15);
    int kb = (ks << 5) + ((lane >> 4) << 3);
    f16x8 h;
#pragma unroll
    for (int j = 0; j < 8; ++j)
      h[j] = (_Float16)W_attn[(size_t)(NH + kb + j) * NH + col];
    *(f16x8*)((char*)Bp + (size_t)(((ks << 3) + ws) << 12) + (nj << 10) + (lane << 4)) = h;
  }
}

// Fused  tanh(enc@W_e + c) . W_v  partials.
// R18 body (0-conflict A geometry, BK=64, 16 barriers) + the R14 occupancy:
// __launch_bounds__(512,4) forces <=128 total regs (64 arch + 64 acc) ->
// 4 waves/EU, the 39%-occupancy regime where every fast kernel lived.
__global__ __launch_bounds__(512, 4) void score_kernel(
    const float* __restrict__ enc, const _Float16* __restrict__ Bp,
    const float* __restrict__ c, const float* __restrict__ Wv,
    float* __restrict__ spart) {
  __shared__ float Asm[2][64 * 64];  // fp32, 16 KB each, row stride 256 B
  const int tid = threadIdx.x;
  const int lane = tid & 63;
  const int wid = tid >> 6;        // 0..7 = wave's 64-col slice
  const int r15 = lane & 15;
  const int id = blockIdx.x;                  // 0..511
  const int mt = ((id & 7) << 6) + (id >> 3); // bijective XCD swizzle (512%8==0)
  const int b = mt >> 4;
  const int s0 = (mt & 15) << 6;
  const char* Abase = (const char*)(enc + ((size_t)b * NS + s0) * NE);  // 4096 B rows
  const char* Bbase = (const char*)Bp + ((size_t)wid << 12);  // this slice's stream

  f32x4 acc[4][4];
#pragma unroll
  for (int i = 0; i < 4; ++i)
#pragma unroll
    for (int j = 0; j < 4; ++j) acc[i][j] = (f32x4)0.f;

  // A LDS (R8/R9/R18-verified 0-conflict): byte d holds linear src
  // (row = d>>8, in-row = (d&255) ^ ((row&15)<<4)). Step = 64x64 fp32 = 16 KB;
  // 512 thr x 16 B x 2 passes. KT = 0..15.
#define STAGE_A(KT, BUF)                                                         \
  _Pragma("unroll") for (int i = 0; i < 2; ++i) {                                \
    int d = (i << 13) + (tid << 4);                                              \
    int row = d >> 8;                                                            \
    int sb = (d & 255) ^ ((row & 15) << 4);                                      \
    __builtin_amdgcn_global_load_lds(                                            \
        (const __attribute__((address_space(1))) uint32_t*)(Abase + (size_t)row * 4096 + ((size_t)(KT) << 8) + sb), \
        (__attribute__((address_space(3))) uint32_t*)((char*)Asm[BUF] + (i << 13) + (wid << 10)), \
        16, 0, 0);                                                               \
  }

  // B fragments for k-slice KS (0..31): 4 contiguous dwordx4 per lane.
#define BLOAD(ARR, KS)                                                           \
  _Pragma("unroll") for (int nj = 0; nj < 4; ++nj)                               \
      ARR[nj] = *(const f16x8*)(Bbase + ((size_t)(KS) << 15) +                   \
                                (nj << 10) + (lane << 4));

  // One k-slice (16 MFMA): af from Asm[CUR] half KK (R18-verified formulas).
#define COMPUTE_KK(CUR, KK, ARR)                                                 \
  _Pragma("unroll") for (int mi = 0; mi < 4; ++mi) {                             \
    int row = (mi << 4) + r15;                                                   \
    int off1 = (row << 8) + ((KK) << 7) + ((lane >> 4) << 5);                    \
    int x = (row & 15) << 4;                                                     \
    f32x4 u = *(const f32x4*)((const char*)Asm[CUR] + (off1 ^ x));               \
    f32x4 v = *(const f32x4*)((const char*)Asm[CUR] + ((off1 + 16) ^ x));        \
    f16x8 h;                                                                     \
    h[0] = (_Float16)u[0]; h[1] = (_Float16)u[1];                                \
    h[2] = (_Float16)u[2]; h[3] = (_Float16)u[3];                                \
    h[4] = (_Float16)v[0]; h[5] = (_Float16)v[1];                                \
    h[6] = (_Float16)v[2]; h[7] = (_Float16)v[3];                                \
    _Pragma("unroll") for (int nj = 0; nj < 4; ++nj)                             \
      acc[mi][nj] = __builtin_amdgcn_mfma_f32_16x16x32_f16(h, ARR[nj],           \
                                                           acc[mi][nj], 0, 0, 0); \
  }

  f16x8 bfE[4], bfO[4];
  STAGE_A(0, 0);
  BLOAD(bfE, 0);
  __syncthreads();
  // Pair-unrolled over 16 BK=64 steps; one __syncthreads per step.
  for (int kt = 0; kt < 16; kt += 2) {
    // ---- even step kt (buf 0): slices 2kt (bfE), 2kt+1 (bfO) ----
    STAGE_A(kt + 1, 1);                 // A prefetch: covered by whole step
    BLOAD(bfO, (kt << 1) + 1);          // covered by kk=0 MFMAs
    COMPUTE_KK(0, 0, bfE);
    BLOAD(bfE, (kt << 1) + 2);          // next step's first slice
    COMPUTE_KK(0, 1, bfO);
    __syncthreads();                    // drains A(kt+1) + all B loads
    // ---- odd step kt+1 (buf 1): slices 2kt+2 (bfE), 2kt+3 (bfO) ----
    if (kt < 14) STAGE_A(kt + 2, 0);
    BLOAD(bfO, (kt << 1) + 3);
    COMPUTE_KK(1, 0, bfE);
    if (kt < 14) BLOAD(bfE, (kt << 1) + 4);
    COMPUTE_KK(1, 1, bfO);
    __syncthreads();
  }
#undef STAGE_A
#undef BLOAD
#undef COMPUTE_KK

  // ---- epilogue (R14 verbatim): fast-tanh + W_v dot over this wave's 64 cols ----
  float sr[4][4];
#pragma unroll
  for (int i = 0; i < 4; ++i)
#pragma unroll
    for (int r = 0; r < 4; ++r) sr[i][r] = 0.f;
#pragma unroll
  for (int nj = 0; nj < 4; ++nj) {
    int hcol = (wid << 6) + (nj << 4) + r15;
    float wvj = Wv[hcol];
    float cvj = c[b * NH + hcol];
#pragma unroll
    for (int mi = 0; mi < 4; ++mi)
#pragma unroll
      for (int r = 0; r < 4; ++r)
        sr[mi][r] += wvj * fast_tanh(acc[mi][nj][r] + cvj);
  }
  // reduce across the 16 col-lanes (fixed order -> deterministic)
#pragma unroll
  for (int off = 1; off < 16; off <<= 1)
#pragma unroll
    for (int mi = 0; mi < 4; ++mi)
#pragma unroll
      for (int r = 0; r < 4; ++r) sr[mi][r] += __shfl_xor(sr[mi][r], off, 64);
  if (r15 == 0) {
    float* dst = spart + (size_t)wid * NB * NS + b * NS + s0;
#pragma unroll
    for (int mi = 0; mi < 4; ++mi)
#pragma unroll
      for (int r = 0; r < 4; ++r)
        dst[(mi << 4) + ((lane >> 4) << 2) + r] = sr[mi][r];
  }
}

// masked softmax over S per batch row; sums the 8 score partials first
__global__ __launch_bounds__(256) void softmax_kernel(
    const float* __restrict__ spart, const int* __restrict__ mask,
    float* __restrict__ attn) {
  int b = blockIdx.x, tid = threadIdx.x;
  __shared__ float red[8];
  float v[4];
  float mx = -INFINITY;
#pragma unroll
  for (int j = 0; j < 4; ++j) {
    int s = tid + (j << 8);
    float x = 0.f;
#pragma unroll
    for (int p = 0; p < 8; ++p) x += spart[(size_t)p * NB * NS + b * NS + s];
    v[j] = (mask[b * NS + s] == 0) ? NEGV : x;
    mx = fmaxf(mx, v[j]);
  }
#pragma unroll
  for (int off = 32; off >= 1; off >>= 1) mx = fmaxf(mx, __shfl_xor(mx, off, 64));
  if ((tid & 63) == 0) red[tid >> 6] = mx;
  __syncthreads();
  mx = fmaxf(fmaxf(red[0], red[1]), fmaxf(red[2], red[3]));
  float sum = 0.f;
#pragma unroll
  for (int j = 0; j < 4; ++j) {
    v[j] = __expf(v[j] - mx);
    sum += v[j];
  }
#pragma unroll
  for (int off = 32; off >= 1; off >>= 1) sum += __shfl_xor(sum, off, 64);
  __syncthreads();
  if ((tid & 63) == 0) red[4 + (tid >> 6)] = sum;
  __syncthreads();
  float inv = 1.f / (red[4] + red[5] + red[6] + red[7]);
#pragma unroll
  for (int j = 0; j < 4; ++j) attn[b * NS + tid + (j << 8)] = v[j] * inv;
}

// partial context over a 64-row S chunk (fp32 enc)
__global__ __launch_bounds__(256) void ctx_partial_kernel(
    const float* __restrict__ enc, const float* __restrict__ attn,
    float* __restrict__ partial) {
  int ch = blockIdx.x;  // 0..15
  int b = blockIdx.y;
  int tid = threadIdx.x;
  __shared__ float w[64];
  if (tid < 64) w[tid] = attn[b * NS + (ch << 6) + tid];
  __syncthreads();
  const float* encb = enc + ((size_t)b * NS + (ch << 6)) * NE;
  float4 acc = make_float4(0.f, 0.f, 0.f, 0.f);
  int e = tid << 2;
  for (int s = 0; s < 64; ++s) {
    float4 x = *(const float4*)(encb + (size_t)s * NE + e);
    float ws_ = w[s];
    acc.x = fmaf(ws_, x.x, acc.x);
    acc.y = fmaf(ws_, x.y, acc.y);
    acc.z = fmaf(ws_, x.z, acc.z);
    acc.w = fmaf(ws_, x.w, acc.w);
  }
  *(float4*)(partial + ((size_t)(b * 16 + ch)) * NE + e) = acc;
}

__global__ __launch_bounds__(256) void ctx_reduce_kernel(
    const float* __restrict__ partial, float* __restrict__ ctx) {
  int b = blockIdx.x;
  int e = threadIdx.x << 2;
  float4 acc = make_float4(0.f, 0.f, 0.f, 0.f);
  for (int ch = 0; ch < 16; ++ch) {
    float4 x = *(const float4*)(partial + ((size_t)(b * 16 + ch)) * NE + e);
    acc.x += x.x;
    acc.y += x.y;
    acc.z += x.z;
    acc.w += x.w;
  }
  *(float4*)(ctx + (size_t)b * NE + e) = acc;
}

extern "C" void kernel_launch(void* const* d_in, const int* in_sizes, int n_in,
                              void* d_out, int out_size, void* d_ws, size_t ws_size,
                              hipStream_t stream) {
  const float* hidden = (const float*)d_in[0];
  const float* enc = (const float*)d_in[1];
  const int* mask = (const int*)d_in[2];
  const float* W_attn = (const float*)d_in[3];
  const float* b_attn = (const float*)d_in[4];
  const float* W_v = (const float*)d_in[5];

  float* ctx = (float*)d_out;   // context: 32*1024
  float* attn = ctx + NB * NS;  // attn_w: 32*1024

  char* ws = (char*)d_ws;
  float* c = (float*)ws;                             // 64 KB
  float* spart = (float*)(ws + 65536);               // 8*32*1024 f32 = 1 MB
  float* partial = (float*)(ws + 65536 + 1048576);   // 32*16*1024 f32 = 2 MB
  _Float16* Bp = (_Float16*)(ws + 65536 + 1048576 + 2097152);  // 1 MB packed

  proj_h_kernel<<<64, 256, 0, stream>>>(hidden, W_attn, b_attn, c);
  prep_We_kernel<<<32, 256, 0, stream>>>(W_attn, Bp);
  score_kernel<<<512, 512, 0, stream>>>(enc, Bp, c, W_v, spart);
  softmax_kernel<<<NB, 256, 0, stream>>>(spart, mask, attn);
  ctx_partial_kernel<<<dim3(16, NB), 256, 0, stream>>>(enc, attn, partial);
  ctx_reduce_kernel<<<NB, 256, 0, stream>>>(partial, ctx);
}

// Round 20
// 106.729 us; speedup vs baseline: 1.1913x; 1.1913x over previous
//
#include <hip/hip_runtime.h>
#include <hip/hip_bf16.h>
#include <math.h>

#define NB 32
#define NS 1024
#define NH 512
#define NE 1024   // 2H
#define NEGV -1e10f

typedef _Float16 f16x8 __attribute__((ext_vector_type(8)));
typedef _Float16 f16x4 __attribute__((ext_vector_type(4)));
typedef float f32x4 __attribute__((ext_vector_type(4)));

__device__ __forceinline__ float fast_tanh(float x) {
  float t = __expf(2.f * x);
  return (t - 1.f) * __builtin_amdgcn_rcpf(t + 1.f);
}

// c[b][h] = b_attn[h] + sum_e hidden[b][e] * W_h[e][h]   (fp32, tiny)
__global__ __launch_bounds__(256) void proj_h_kernel(
    const float* __restrict__ hidden, const float* __restrict__ W_attn,
    const float* __restrict__ b_attn, float* __restrict__ c) {
  int b = blockIdx.x >> 1;
  int h = ((blockIdx.x & 1) << 8) + threadIdx.x;
  __shared__ float hid[NH];
  for (int e = threadIdx.x; e < NH; e += 256) hid[e] = hidden[b * NH + e];
  __syncthreads();
  float acc = b_attn[h];
#pragma unroll 8
  for (int e = 0; e < NH; ++e) acc = fmaf(hid[e], W_attn[(size_t)e * NH + h], acc);
  c[b * NH + h] = acc;
}

// Pack W_e into MFMA B-fragment order. BYTE layout (R14-verified):
//   (ks*8 + wslice)*4096 + nj*1024 + lane*16  <-  halfs j=0..7 of
//   W_e[ks*32 + (lane>>4)*8 + j][wslice*64 + nj*16 + (lane&15)]
__global__ __launch_bounds__(256) void prep_We_kernel(
    const float* __restrict__ W_attn, _Float16* __restrict__ Bp) {
  int ks = blockIdx.x;  // 0..31
  int t = threadIdx.x;
#pragma unroll
  for (int p = 0; p < 8; ++p) {
    int f = (p << 8) + t;        // 0..2047
    int ws = f >> 8;             // 0..7  (64-col slice)
    int nj = (f >> 6) & 3;       // 0..3
    int lane = f & 63;
    int col = (ws << 6) + (nj << 4) + (lane & 15);
    int kb = (ks << 5) + ((lane >> 4) << 3);
    f16x8 h;
#pragma unroll
    for (int j = 0; j < 8; ++j)
      h[j] = (_Float16)W_attn[(size_t)(NH + kb + j) * NH + col];
    *(f16x8*)((char*)Bp + (size_t)(((ks << 3) + ws) << 12) + (nj << 10) + (lane << 4)) = h;
  }
}

// Fused  tanh(enc@W_e + c) . W_v  partials.
// NEW STRUCTURE (R6 A-path + R14 B-path):
//   BM=64, BN=512, 512 thr / 8 waves (wave 64x64, acc 4x4).
//   Phase 1: stage the ENTIRE 64x1024 A-panel once — CONTIGUOUS 4 KB-row
//     float4 reads (streaming HBM, no 256B/4KB-stride tax), cvt fp16,
//     XOR-swizzled 128 KB LDS. One barrier total.
//   Phase 2: barrier-free K-loop — af = 1 ds_read_b128 per frag (fp16, no
//     in-loop cvt), B = packed-Bp register stream (contiguous 16B/lane).
__global__ __launch_bounds__(512) void score_kernel(
    const float* __restrict__ enc, const _Float16* __restrict__ Bp,
    const float* __restrict__ c, const float* __restrict__ Wv,
    float* __restrict__ spart) {
  __shared__ _Float16 Afp16[64 * 1024];  // 128 KB, row stride 2048 B, swizzled
  const int tid = threadIdx.x;
  const int lane = tid & 63;
  const int wid = tid >> 6;        // 0..7 = wave's 64-col slice
  const int r15 = lane & 15;
  const int id = blockIdx.x;                  // 0..511
  const int mt = ((id & 7) << 6) + (id >> 3); // bijective XCD swizzle (512%8==0)
  const int b = mt >> 4;
  const int s0 = (mt & 15) << 6;
  const float* encb = enc + ((size_t)b * NS + s0) * NE;
  const char* Bbase = (const char*)Bp + ((size_t)wid << 12);  // this slice's stream

  // ---- Phase 1: stage A-panel, fully contiguous reads ----
  // pass p: float4 index f = p*512+tid; row = f>>8 (256 float4/row), kq = f&255.
  // LDS byte = row*2048 + kq*8, XOR (row&7)<<4 (8B blocks preserved: XOR bits>=4).
#pragma unroll 4
  for (int p = 0; p < 32; ++p) {
    int f = (p << 9) + tid;
    int row = f >> 8;
    int kq = f & 255;
    float4 v = *(const float4*)(encb + ((size_t)row << 10) + (kq << 2));
    f16x4 h;
    h[0] = (_Float16)v.x; h[1] = (_Float16)v.y;
    h[2] = (_Float16)v.z; h[3] = (_Float16)v.w;
    int off = (row << 11) + (kq << 3);
    off ^= (row & 7) << 4;
    *(f16x4*)((char*)Afp16 + off) = h;
  }
  __syncthreads();  // the only barrier

  f32x4 acc[4][4];
#pragma unroll
  for (int i = 0; i < 4; ++i)
#pragma unroll
    for (int j = 0; j < 4; ++j) acc[i][j] = (f32x4)0.f;

  // B fragments for k-slice KS (0..31): 4 contiguous dwordx4 per lane.
#define BLOAD(ARR, KS)                                                           \
  _Pragma("unroll") for (int nj = 0; nj < 4; ++nj)                               \
      ARR[nj] = *(const f16x8*)(Bbase + ((size_t)(KS) << 15) +                   \
                                (nj << 10) + (lane << 4));

  // One k-slice (16 MFMA): af[mi] = one ds_read_b128 at
  // row=(mi*16)+r15, byte = row*2048 + KS*64 + (lane>>4)*16, XOR (row&7)<<4.
#define COMPUTE(KS, ARR)                                                         \
  {                                                                              \
    f16x8 af[4];                                                                 \
    _Pragma("unroll") for (int mi = 0; mi < 4; ++mi) {                           \
      int row = (mi << 4) + r15;                                                 \
      int off = (row << 11) + ((KS) << 6) + ((lane >> 4) << 4);                  \
      off ^= (row & 7) << 4;                                                     \
      af[mi] = *(const f16x8*)((const char*)Afp16 + off);                        \
    }                                                                            \
    _Pragma("unroll") for (int mi = 0; mi < 4; ++mi)                             \
      _Pragma("unroll") for (int nj = 0; nj < 4; ++nj)                           \
        acc[mi][nj] = __builtin_amdgcn_mfma_f32_16x16x32_f16(af[mi], ARR[nj],    \
                                                             acc[mi][nj], 0, 0, 0); \
  }

  // ---- Phase 2: barrier-free K-loop, static bf rotation (rule #20) ----
  f16x8 bfE[4], bfO[4];
  BLOAD(bfE, 0);
  for (int ks = 0; ks < 32; ks += 2) {
    BLOAD(bfO, ks + 1);
    COMPUTE(ks, bfE);
    if (ks < 30) BLOAD(bfE, ks + 2);
    COMPUTE(ks + 1, bfO);
  }
#undef BLOAD
#undef COMPUTE

  // ---- epilogue (R14 verbatim): fast-tanh + W_v dot over this wave's 64 cols ----
  float sr[4][4];
#pragma unroll
  for (int i = 0; i < 4; ++i)
#pragma unroll
    for (int r = 0; r < 4; ++r) sr[i][r] = 0.f;
#pragma unroll
  for (int nj = 0; nj < 4; ++nj) {
    int hcol = (wid << 6) + (nj << 4) + r15;
    float wvj = Wv[hcol];
    float cvj = c[b * NH + hcol];
#pragma unroll
    for (int mi = 0; mi < 4; ++mi)
#pragma unroll
      for (int r = 0; r < 4; ++r)
        sr[mi][r] += wvj * fast_tanh(acc[mi][nj][r] + cvj);
  }
  // reduce across the 16 col-lanes (fixed order -> deterministic)
#pragma unroll
  for (int off = 1; off < 16; off <<= 1)
#pragma unroll
    for (int mi = 0; mi < 4; ++mi)
#pragma unroll
      for (int r = 0; r < 4; ++r) sr[mi][r] += __shfl_xor(sr[mi][r], off, 64);
  if (r15 == 0) {
    float* dst = spart + (size_t)wid * NB * NS + b * NS + s0;
#pragma unroll
    for (int mi = 0; mi < 4; ++mi)
#pragma unroll
      for (int r = 0; r < 4; ++r)
        dst[(mi << 4) + ((lane >> 4) << 2) + r] = sr[mi][r];
  }
}

// masked softmax over S per batch row; sums the 8 score partials first
__global__ __launch_bounds__(256) void softmax_kernel(
    const float* __restrict__ spart, const int* __restrict__ mask,
    float* __restrict__ attn) {
  int b = blockIdx.x, tid = threadIdx.x;
  __shared__ float red[8];
  float v[4];
  float mx = -INFINITY;
#pragma unroll
  for (int j = 0; j < 4; ++j) {
    int s = tid + (j << 8);
    float x = 0.f;
#pragma unroll
    for (int p = 0; p < 8; ++p) x += spart[(size_t)p * NB * NS + b * NS + s];
    v[j] = (mask[b * NS + s] == 0) ? NEGV : x;
    mx = fmaxf(mx, v[j]);
  }
#pragma unroll
  for (int off = 32; off >= 1; off >>= 1) mx = fmaxf(mx, __shfl_xor(mx, off, 64));
  if ((tid & 63) == 0) red[tid >> 6] = mx;
  __syncthreads();
  mx = fmaxf(fmaxf(red[0], red[1]), fmaxf(red[2], red[3]));
  float sum = 0.f;
#pragma unroll
  for (int j = 0; j < 4; ++j) {
    v[j] = __expf(v[j] - mx);
    sum += v[j];
  }
#pragma unroll
  for (int off = 32; off >= 1; off >>= 1) sum += __shfl_xor(sum, off, 64);
  __syncthreads();
  if ((tid & 63) == 0) red[4 + (tid >> 6)] = sum;
  __syncthreads();
  float inv = 1.f / (red[4] + red[5] + red[6] + red[7]);
#pragma unroll
  for (int j = 0; j < 4; ++j) attn[b * NS + tid + (j << 8)] = v[j] * inv;
}

// partial context over a 64-row S chunk (fp32 enc)
__global__ __launch_bounds__(256) void ctx_partial_kernel(
    const float* __restrict__ enc, const float* __restrict__ attn,
    float* __restrict__ partial) {
  int ch = blockIdx.x;  // 0..15
  int b = blockIdx.y;
  int tid = threadIdx.x;
  __shared__ float w[64];
  if (tid < 64) w[tid] = attn[b * NS + (ch << 6) + tid];
  __syncthreads();
  const float* encb = enc + ((size_t)b * NS + (ch << 6)) * NE;
  float4 acc = make_float4(0.f, 0.f, 0.f, 0.f);
  int e = tid << 2;
  for (int s = 0; s < 64; ++s) {
    float4 x = *(const float4*)(encb + (size_t)s * NE + e);
    float ws_ = w[s];
    acc.x = fmaf(ws_, x.x, acc.x);
    acc.y = fmaf(ws_, x.y, acc.y);
    acc.z = fmaf(ws_, x.z, acc.z);
    acc.w = fmaf(ws_, x.w, acc.w);
  }
  *(float4*)(partial + ((size_t)(b * 16 + ch)) * NE + e) = acc;
}

__global__ __launch_bounds__(256) void ctx_reduce_kernel(
    const float* __restrict__ partial, float* __restrict__ ctx) {
  int b = blockIdx.x;
  int e = threadIdx.x << 2;
  float4 acc = make_float4(0.f, 0.f, 0.f, 0.f);
  for (int ch = 0; ch < 16; ++ch) {
    float4 x = *(const float4*)(partial + ((size_t)(b * 16 + ch)) * NE + e);
    acc.x += x.x;
    acc.y += x.y;
    acc.z += x.z;
    acc.w += x.w;
  }
  *(float4*)(ctx + (size_t)b * NE + e) = acc;
}

extern "C" void kernel_launch(void* const* d_in, const int* in_sizes, int n_in,
                              void* d_out, int out_size, void* d_ws, size_t ws_size,
                              hipStream_t stream) {
  const float* hidden = (const float*)d_in[0];
  const float* enc = (const float*)d_in[1];
  const int* mask = (const int*)d_in[2];
  const float* W_attn = (const float*)d_in[3];
  const float* b_attn = (const float*)d_in[4];
  const float* W_v = (const float*)d_in[5];

  float* ctx = (float*)d_out;   // context: 32*1024
  float* attn = ctx + NB * NS;  // attn_w: 32*1024

  char* ws = (char*)d_ws;
  float* c = (float*)ws;                             // 64 KB
  float* spart = (float*)(ws + 65536);               // 8*32*1024 f32 = 1 MB
  float* partial = (float*)(ws + 65536 + 1048576);   // 32*16*1024 f32 = 2 MB
  _Float16* Bp = (_Float16*)(ws + 65536 + 1048576 + 2097152);  // 1 MB packed

  proj_h_kernel<<<64, 256, 0, stream>>>(hidden, W_attn, b_attn, c);
  prep_We_kernel<<<32, 256, 0, stream>>>(W_attn, Bp);
  score_kernel<<<512, 512, 0, stream>>>(enc, Bp, c, W_v, spart);
  softmax_kernel<<<NB, 256, 0, stream>>>(spart, mask, attn);
  ctx_partial_kernel<<<dim3(16, NB), 256, 0, stream>>>(enc, attn, partial);
  ctx_reduce_kernel<<<NB, 256, 0, stream>>>(partial, ctx);
}

// Round 21
// 105.939 us; speedup vs baseline: 1.2002x; 1.0075x over previous
//
#include <hip/hip_runtime.h>
#include <hip/hip_bf16.h>
#include <math.h>

#define NB 32
#define NS 1024
#define NH 512
#define NE 1024   // 2H
#define NEGV -1e10f

typedef _Float16 f16x8 __attribute__((ext_vector_type(8)));
typedef _Float16 f16x4 __attribute__((ext_vector_type(4)));
typedef float f32x4 __attribute__((ext_vector_type(4)));

__device__ __forceinline__ float fast_tanh(float x) {
  float t = __expf(2.f * x);
  return (t - 1.f) * __builtin_amdgcn_rcpf(t + 1.f);
}

// c[b][h] = b_attn[h] + sum_e hidden[b][e] * W_h[e][h]   (fp32, tiny)
__global__ __launch_bounds__(256) void proj_h_kernel(
    const float* __restrict__ hidden, const float* __restrict__ W_attn,
    const float* __restrict__ b_attn, float* __restrict__ c) {
  int b = blockIdx.x >> 1;
  int h = ((blockIdx.x & 1) << 8) + threadIdx.x;
  __shared__ float hid[NH];
  for (int e = threadIdx.x; e < NH; e += 256) hid[e] = hidden[b * NH + e];
  __syncthreads();
  float acc = b_attn[h];
#pragma unroll 8
  for (int e = 0; e < NH; ++e) acc = fmaf(hid[e], W_attn[(size_t)e * NH + h], acc);
  c[b * NH + h] = acc;
}

// Pack W_e into MFMA B-fragment order. BYTE layout (R14-verified):
//   (ks*8 + wslice)*4096 + nj*1024 + lane*16  <-  halfs j=0..7 of
//   W_e[ks*32 + (lane>>4)*8 + j][wslice*64 + nj*16 + (lane&15)]
__global__ __launch_bounds__(256) void prep_We_kernel(
    const float* __restrict__ W_attn, _Float16* __restrict__ Bp) {
  int ks = blockIdx.x;  // 0..31
  int t = threadIdx.x;
#pragma unroll
  for (int p = 0; p < 8; ++p) {
    int f = (p << 8) + t;        // 0..2047
    int ws = f >> 8;             // 0..7  (64-col slice)
    int nj = (f >> 6) & 3;       // 0..3
    int lane = f & 63;
    int col = (ws << 6) + (nj << 4) + (lane & 15);
    int kb = (ks << 5) + ((lane >> 4) << 3);
    f16x8 h;
#pragma unroll
    for (int j = 0; j < 8; ++j)
      h[j] = (_Float16)W_attn[(size_t)(NH + kb + j) * NH + col];
    *(f16x8*)((char*)Bp + (size_t)(((ks << 3) + ws) << 12) + (nj << 10) + (lane << 4)) = h;
  }
}

// Fused  tanh(enc@W_e + c) . W_v  partials.
// R20 structure (contiguous A-panel stage + barrier-free MFMA loop + packed-B
// register stream) with two latency fixes:
//  1) B prefetch depth-3: 4 static register sets, issue slice s+3 before
//     computing s (~300+ cy cover vs L2 latency). Regs are free: 128 KB LDS
//     caps the CU at 8 waves regardless, so up to 256 regs/thread cost nothing.
//  2) A-panel staged in TWO 64 KB halves; half-1's staging (batch-pipelined
//     reg loads + ds_writes) overlaps half-0's compute. 3 barriers total.
__global__ __launch_bounds__(512) void score_kernel(
    const float* __restrict__ enc, const _Float16* __restrict__ Bp,
    const float* __restrict__ c, const float* __restrict__ Wv,
    float* __restrict__ spart) {
  __shared__ _Float16 Afp16[64 * 1024];  // 128 KB = 2 halves x (64 rows x 512 k), row stride 1024 B
  const int tid = threadIdx.x;
  const int lane = tid & 63;
  const int wid = tid >> 6;        // 0..7 = wave's 64-col slice
  const int r15 = lane & 15;
  const int id = blockIdx.x;                  // 0..511
  const int mt = ((id & 7) << 6) + (id >> 3); // bijective XCD swizzle (512%8==0)
  const int b = mt >> 4;
  const int s0 = (mt & 15) << 6;
  const char* encB = (const char*)(enc + ((size_t)b * NS + s0) * NE);  // 4096 B rows
  const char* Bbase = (const char*)Bp + ((size_t)wid << 12);  // this slice's stream

  f32x4 acc[4][4];
#pragma unroll
  for (int i = 0; i < 4; ++i)
#pragma unroll
    for (int j = 0; j < 4; ++j) acc[i][j] = (f32x4)0.f;

  // Stage batch LB (4 passes) of half H: 4 float4/thread. Pass p: f = (4LB+p)*512+tid,
  // row = f>>7, kq = f&127 (float4 idx in the 512-float half).
#define LOADB(V, H, LB)                                                          \
  _Pragma("unroll") for (int p = 0; p < 4; ++p) {                                \
    int f = ((((LB) << 2) + p) << 9) + tid;                                      \
    int row = f >> 7;                                                            \
    int kq = f & 127;                                                            \
    V[p] = *(const float4*)(encB + (size_t)row * 4096 + ((H) << 11) + (kq << 4));\
  }

#define WRITEB(V, H, LB)                                                         \
  _Pragma("unroll") for (int p = 0; p < 4; ++p) {                                \
    int f = ((((LB) << 2) + p) << 9) + tid;                                      \
    int row = f >> 7;                                                            \
    int kq = f & 127;                                                            \
    f16x4 h4;                                                                    \
    h4[0] = (_Float16)V[p].x; h4[1] = (_Float16)V[p].y;                          \
    h4[2] = (_Float16)V[p].z; h4[3] = (_Float16)V[p].w;                          \
    int off = ((H) << 16) + (row << 10) + (kq << 3);                             \
    off ^= (row & 7) << 4;                                                       \
    *(f16x4*)((char*)Afp16 + off) = h4;                                          \
  }

  // B fragments for global k-slice KS (0..31): 4 contiguous dwordx4 per lane.
#define BLOAD(ARR, KS)                                                           \
  _Pragma("unroll") for (int nj = 0; nj < 4; ++nj)                               \
      ARR[nj] = *(const f16x8*)(Bbase + ((size_t)(KS) << 15) +                   \
                                (nj << 10) + (lane << 4));

  // One k-slice (16 MFMA) on half H, local slice KSL (0..15).
#define COMPUTE(H, KSL, ARR)                                                     \
  {                                                                              \
    f16x8 af[4];                                                                 \
    _Pragma("unroll") for (int mi = 0; mi < 4; ++mi) {                           \
      int row = (mi << 4) + r15;                                                 \
      int off = ((H) << 16) + (row << 10) + ((KSL) << 6) + ((lane >> 4) << 4);   \
      off ^= (row & 7) << 4;                                                     \
      af[mi] = *(const f16x8*)((const char*)Afp16 + off);                        \
    }                                                                            \
    _Pragma("unroll") for (int mi = 0; mi < 4; ++mi)                             \
      _Pragma("unroll") for (int nj = 0; nj < 4; ++nj)                           \
        acc[mi][nj] = __builtin_amdgcn_mfma_f32_16x16x32_f16(af[mi], ARR[nj],    \
                                                             acc[mi][nj], 0, 0, 0); \
  }

  // ---- Phase 1: stage half-0 (2-set batch pipeline, contiguous reads) ----
  {
    float4 vA[4], vB[4];
    LOADB(vA, 0, 0); LOADB(vB, 0, 1);
    WRITEB(vA, 0, 0); LOADB(vA, 0, 2);
    WRITEB(vB, 0, 1); LOADB(vB, 0, 3);
    WRITEB(vA, 0, 2); WRITEB(vB, 0, 3);
  }
  __syncthreads();

  f16x8 S0[4], S1[4], S2[4], S3[4];
  BLOAD(S0, 0); BLOAD(S1, 1); BLOAD(S2, 2);

  float4 vS[4];
  // ---- half-0 compute (global slices 0..15) + half-1 staging interleave ----
  for (int g = 0; g < 4; ++g) {
    int s = g << 2;
    BLOAD(S3, s + 3);
    LOADB(vS, 1, g);              // half-1 batch g: consumed 3 slices later
    COMPUTE(0, s + 0, S0);
    BLOAD(S0, s + 4);
    COMPUTE(0, s + 1, S1);
    BLOAD(S1, s + 5);
    COMPUTE(0, s + 2, S2);
    BLOAD(S2, s + 6);
    WRITEB(vS, 1, g);
    COMPUTE(0, s + 3, S3);
  }
  __syncthreads();  // half-1 writes landed; S0..S2 hold slices 16,17,18
  // ---- half-1 compute (global slices 16..31, local 0..15) ----
  for (int g = 0; g < 4; ++g) {
    int s = 16 + (g << 2);
    int k0 = s + 3;               // ≤ 31 always (max s = 28)
    int k1 = s + 4 > 31 ? 31 : s + 4;   // phantom re-load of 31 on tail
    int k2 = s + 5 > 31 ? 31 : s + 5;
    int k3 = s + 6 > 31 ? 31 : s + 6;
    BLOAD(S3, k0);
    COMPUTE(1, (g << 2) + 0, S0);
    BLOAD(S0, k1);
    COMPUTE(1, (g << 2) + 1, S1);
    BLOAD(S1, k2);
    COMPUTE(1, (g << 2) + 2, S2);
    BLOAD(S2, k3);
    COMPUTE(1, (g << 2) + 3, S3);
  }
#undef LOADB
#undef WRITEB
#undef BLOAD
#undef COMPUTE

  // ---- epilogue (R14/R20 verbatim): fast-tanh + W_v dot over this wave's 64 cols ----
  float sr[4][4];
#pragma unroll
  for (int i = 0; i < 4; ++i)
#pragma unroll
    for (int r = 0; r < 4; ++r) sr[i][r] = 0.f;
#pragma unroll
  for (int nj = 0; nj < 4; ++nj) {
    int hcol = (wid << 6) + (nj << 4) + r15;
    float wvj = Wv[hcol];
    float cvj = c[b * NH + hcol];
#pragma unroll
    for (int mi = 0; mi < 4; ++mi)
#pragma unroll
      for (int r = 0; r < 4; ++r)
        sr[mi][r] += wvj * fast_tanh(acc[mi][nj][r] + cvj);
  }
  // reduce across the 16 col-lanes (fixed order -> deterministic)
#pragma unroll
  for (int off = 1; off < 16; off <<= 1)
#pragma unroll
    for (int mi = 0; mi < 4; ++mi)
#pragma unroll
      for (int r = 0; r < 4; ++r) sr[mi][r] += __shfl_xor(sr[mi][r], off, 64);
  if (r15 == 0) {
    float* dst = spart + (size_t)wid * NB * NS + b * NS + s0;
#pragma unroll
    for (int mi = 0; mi < 4; ++mi)
#pragma unroll
      for (int r = 0; r < 4; ++r)
        dst[(mi << 4) + ((lane >> 4) << 2) + r] = sr[mi][r];
  }
}

// masked softmax over S per batch row; sums the 8 score partials first
__global__ __launch_bounds__(256) void softmax_kernel(
    const float* __restrict__ spart, const int* __restrict__ mask,
    float* __restrict__ attn) {
  int b = blockIdx.x, tid = threadIdx.x;
  __shared__ float red[8];
  float v[4];
  float mx = -INFINITY;
#pragma unroll
  for (int j = 0; j < 4; ++j) {
    int s = tid + (j << 8);
    float x = 0.f;
#pragma unroll
    for (int p = 0; p < 8; ++p) x += spart[(size_t)p * NB * NS + b * NS + s];
    v[j] = (mask[b * NS + s] == 0) ? NEGV : x;
    mx = fmaxf(mx, v[j]);
  }
#pragma unroll
  for (int off = 32; off >= 1; off >>= 1) mx = fmaxf(mx, __shfl_xor(mx, off, 64));
  if ((tid & 63) == 0) red[tid >> 6] = mx;
  __syncthreads();
  mx = fmaxf(fmaxf(red[0], red[1]), fmaxf(red[2], red[3]));
  float sum = 0.f;
#pragma unroll
  for (int j = 0; j < 4; ++j) {
    v[j] = __expf(v[j] - mx);
    sum += v[j];
  }
#pragma unroll
  for (int off = 32; off >= 1; off >>= 1) sum += __shfl_xor(sum, off, 64);
  __syncthreads();
  if ((tid & 63) == 0) red[4 + (tid >> 6)] = sum;
  __syncthreads();
  float inv = 1.f / (red[4] + red[5] + red[6] + red[7]);
#pragma unroll
  for (int j = 0; j < 4; ++j) attn[b * NS + tid + (j << 8)] = v[j] * inv;
}

// partial context over a 64-row S chunk (fp32 enc)
__global__ __launch_bounds__(256) void ctx_partial_kernel(
    const float* __restrict__ enc, const float* __restrict__ attn,
    float* __restrict__ partial) {
  int ch = blockIdx.x;  // 0..15
  int b = blockIdx.y;
  int tid = threadIdx.x;
  __shared__ float w[64];
  if (tid < 64) w[tid] = attn[b * NS + (ch << 6) + tid];
  __syncthreads();
  const float* encb = enc + ((size_t)b * NS + (ch << 6)) * NE;
  float4 acc = make_float4(0.f, 0.f, 0.f, 0.f);
  int e = tid << 2;
  for (int s = 0; s < 64; ++s) {
    float4 x = *(const float4*)(encb + (size_t)s * NE + e);
    float ws_ = w[s];
    acc.x = fmaf(ws_, x.x, acc.x);
    acc.y = fmaf(ws_, x.y, acc.y);
    acc.z = fmaf(ws_, x.z, acc.z);
    acc.w = fmaf(ws_, x.w, acc.w);
  }
  *(float4*)(partial + ((size_t)(b * 16 + ch)) * NE + e) = acc;
}

__global__ __launch_bounds__(256) void ctx_reduce_kernel(
    const float* __restrict__ partial, float* __restrict__ ctx) {
  int b = blockIdx.x;
  int e = threadIdx.x << 2;
  float4 acc = make_float4(0.f, 0.f, 0.f, 0.f);
  for (int ch = 0; ch < 16; ++ch) {
    float4 x = *(const float4*)(partial + ((size_t)(b * 16 + ch)) * NE + e);
    acc.x += x.x;
    acc.y += x.y;
    acc.z += x.z;
    acc.w += x.w;
  }
  *(float4*)(ctx + (size_t)b * NE + e) = acc;
}

extern "C" void kernel_launch(void* const* d_in, const int* in_sizes, int n_in,
                              void* d_out, int out_size, void* d_ws, size_t ws_size,
                              hipStream_t stream) {
  const float* hidden = (const float*)d_in[0];
  const float* enc = (const float*)d_in[1];
  const int* mask = (const int*)d_in[2];
  const float* W_attn = (const float*)d_in[3];
  const float* b_attn = (const float*)d_in[4];
  const float* W_v = (const float*)d_in[5];

  float* ctx = (float*)d_out;   // context: 32*1024
  float* attn = ctx + NB * NS;  // attn_w: 32*1024

  char* ws = (char*)d_ws;
  float* c = (float*)ws;                             // 64 KB
  float* spart = (float*)(ws + 65536);               // 8*32*1024 f32 = 1 MB
  float* partial = (float*)(ws + 65536 + 1048576);   // 32*16*1024 f32 = 2 MB
  _Float16* Bp = (_Float16*)(ws + 65536 + 1048576 + 2097152);  // 1 MB packed

  proj_h_kernel<<<64, 256, 0, stream>>>(hidden, W_attn, b_attn, c);
  prep_We_kernel<<<32, 256, 0, stream>>>(W_attn, Bp);
  score_kernel<<<512, 512, 0, stream>>>(enc, Bp, c, W_v, spart);
  softmax_kernel<<<NB, 256, 0, stream>>>(spart, mask, attn);
  ctx_partial_kernel<<<dim3(16, NB), 256, 0, stream>>>(enc, attn, partial);
  ctx_reduce_kernel<<<NB, 256, 0, stream>>>(partial, ctx);
}